// Round 16
// baseline (108.587 us; speedup 1.0000x reference)
//
#include <hip/hip_runtime.h>
#include <hip/hip_fp16.h>
#include <hip/hip_bf16.h>
#include <math.h>

#define D 128
#define LDAP 136      // padded LDS row length (bf16 elems)
#define NG 8          // block groups (== XCD count heuristic)
#define GCAP 8        // slots per (row, group); mean sub-degree 1.6
#define OVMAX 4096    // overflow list capacity (expected ~15 entries)

typedef unsigned int   u32;
typedef unsigned short u16;
using f32x4 = __attribute__((ext_vector_type(4))) float;
using s16x8 = __attribute__((ext_vector_type(8))) short;
using u32x4 = __attribute__((ext_vector_type(4))) unsigned int;

__device__ __forceinline__ u16 f2bf(float f) {       // RNE f32->bf16
    u32 u = __float_as_uint(f);
    return (u16)((u + 0x7FFFu + ((u >> 16) & 1u)) >> 16);
}

// ---------------------------------------------------------------------------
// Per-wave int64-vs-int32 edge_index detection (high words of first 64
// elements all zero => int64). Deterministic, same answer in every block.
// ---------------------------------------------------------------------------
__device__ __forceinline__ bool detect_is64(const int* __restrict__ idx32, int E) {
    int lane = threadIdx.x & 63;
    int hi = 0;
    if (lane < E) hi = idx32[2 * lane + 1];
    return __ballot(hi != 0) == 0ull;
}

// ---------------------------------------------------------------------------
// prep+zero: blocks 0..127 transpose W1_top/W2 to bf16; block 128 builds
// w_vec/c_vec + zeroes ovCount; blocks 129.. zero the per-unit COUNTER words
// (packed[unit*16], one per (row,group) unit).
// ---------------------------------------------------------------------------
__global__ __launch_bounds__(128) void prep_zero_kernel(
    const float* __restrict__ W_edge, const float* __restrict__ b_edge,
    const float* __restrict__ W1, const float* __restrict__ b1,
    const float* __restrict__ W2, float* __restrict__ wc,
    u16* __restrict__ Wt1, u16* __restrict__ Wt2,
    u32* __restrict__ packed, int nunits, u32* __restrict__ ovCount)
{
    const int b = blockIdx.x, t = threadIdx.x;
    if (b < D) {
        Wt1[b * D + t] = f2bf(W1[(size_t)t * D + b]);
        Wt2[b * D + t] = f2bf(W2[(size_t)t * D + b]);
    } else if (b == D) {
        if (t == 0) *ovCount = 0u;
        float w = 0.f, c = 0.f;
        #pragma unroll 8
        for (int k = 0; k < D; ++k) {
            float w1 = W1[(size_t)(D + k) * D + t];
            w = fmaf(W_edge[k], w1, w);
            c = fmaf(b_edge[k], w1, c);
        }
        wc[t]     = w;
        wc[D + t] = c + b1[t];
    } else {
        int i = (b - D - 1) * 128 + t;
        if (i < nunits) packed[(size_t)i * 16] = 0u;   // counter word only
    }
}

// ---------------------------------------------------------------------------
// FUSED count + gemm1. Blocks [0,CB): count path, group g = bid & 7
// (XCD-local units). Unit layout: 16 u32 = one 64B line per (row,group):
//   [0]=counter  [8..15]=record slots.
// The atomicAdd pulls the line into the local L2; the record store hits the
// RESIDENT line and merges (R14 falsified pollution; R15 falsified nt —
// this tests residency-at-store-time). Blocks [CB,CB+GB): gemm1 via MFMA.
// ---------------------------------------------------------------------------
__global__ __launch_bounds__(256) void count_gemm1_kernel(
    const void* __restrict__ eidx, const float* __restrict__ coord,
    u32* __restrict__ packed,
    u32* __restrict__ ovCount, u32* __restrict__ ovRow,
    u32* __restrict__ ovRec, int E, int CB,
    const float* __restrict__ A, const u16* __restrict__ Wt,
    u16* __restrict__ ybf, int N)
{
    __shared__ u16 wl[D * LDAP];
    __shared__ u16 al[64 * LDAP];

    if ((int)blockIdx.x < CB) {
        // ---------------- count path ----------------
        const int* idx32 = (const int*)eidx;
        const bool is64 = detect_is64(idx32, E);
        const int g = (int)(blockIdx.x & (NG - 1));
        const int e = blockIdx.x * 256 + threadIdx.x;
        if (e >= E) return;

        // low-word reads only (indices < 2^31)
        int row = is64 ? idx32[2 * e]       : idx32[e];
        int col = is64 ? idx32[2 * (E + e)] : idx32[E + e];

        const size_t base = ((size_t)g * N + row) << 4;   // unit base (16 u32)
        u32 seq = atomicAdd(&packed[base], 1u);           // line now L2-resident

        float dx = coord[3 * row + 0] - coord[3 * col + 0];
        float dy = coord[3 * row + 1] - coord[3 * col + 1];
        float dz = coord[3 * row + 2] - coord[3 * col + 2];
        float dist = sqrtf(fmaf(dx, dx, fmaf(dy, dy, dz * dz)));
        u32 rec = (u32)col | ((u32)__half_as_ushort(__float2half(dist)) << 16);

        if (seq < (u32)GCAP) {
            packed[base + 8 + seq] = rec;                 // same line as atomic
        } else {
            u32 k = atomicAdd(ovCount, 1u);
            if (k < (u32)OVMAX) { ovRow[k] = (u32)row; ovRec[k] = rec; }
        }
        return;
    }

    // ---------------- gemm1 path ----------------
    const int bid  = blockIdx.x - CB;
    const int t    = threadIdx.x;
    const int lane = t & 63;
    const int w    = t >> 6;
    const int n0   = bid * 64;

    #pragma unroll
    for (int i = 0; i < 8; ++i) {
        int e = (i * 256 + t) * 8;
        int r = e >> 7, c = e & 127;
        *(u32x4*)&wl[r * LDAP + c] = *(const u32x4*)&Wt[r * D + c];
    }
    #pragma unroll
    for (int i = 0; i < 8; ++i) {
        int idx = i * 256 + t;
        int r = idx >> 5, c4 = idx & 31;
        int gr = n0 + r; if (gr >= N) gr = N - 1;
        float4 v = *(const float4*)&A[(size_t)gr * D + c4 * 4];
        u32 lo = (u32)f2bf(v.x) | ((u32)f2bf(v.y) << 16);
        u32 hi = (u32)f2bf(v.z) | ((u32)f2bf(v.w) << 16);
        *(uint2*)&al[r * LDAP + c4 * 4] = make_uint2(lo, hi);
    }
    __syncthreads();

    const int  fr     = lane & 15;
    const int  kg     = lane >> 4;
    const bool wvalid = (n0 + w * 16) < N;

    f32x4 acc[8];
    #pragma unroll
    for (int i = 0; i < 8; ++i) acc[i] = (f32x4){0.f, 0.f, 0.f, 0.f};

    #pragma unroll
    for (int kk = 0; kk < 4; ++kk) {
        const int ko = kk * 32 + kg * 8;
        s16x8 a = *(const s16x8*)&al[(w * 16 + fr) * LDAP + ko];
        #pragma unroll
        for (int ct = 0; ct < 8; ++ct) {
            s16x8 b = *(const s16x8*)&wl[(ct * 16 + fr) * LDAP + ko];
            acc[ct] = __builtin_amdgcn_mfma_f32_16x16x32_bf16(a, b, acc[ct], 0, 0, 0);
        }
    }
    if (!wvalid) return;

    #pragma unroll
    for (int ct = 0; ct < 8; ++ct) {
        const int c = ct * 16 + fr;
        #pragma unroll
        for (int j = 0; j < 4; ++j) {
            int R = n0 + w * 16 + 4 * kg + j;
            ybf[(size_t)R * D + c] = f2bf(acc[ct][j]);
        }
    }
}

// ---------------------------------------------------------------------------
// pull aggregation -> H bf16 + degOut. One wave/row; lane owns chans 2l,2l+1.
// Lane l owns unit slot (g=l>>3, j=l&7): counter at unit base, record at
// base+8+j — both from the SAME line (L1 hit for the second). Group prefix
// via 8 shfls; dense-compact into per-wave LDS; then the proven R11 loop.
// ---------------------------------------------------------------------------
__global__ __launch_bounds__(256) void aggregate_kernel(
    const u16* __restrict__ ybf, const u32* __restrict__ packed,
    const float* __restrict__ wc,
    u32* __restrict__ Hb2, u32* __restrict__ degOut,
    const u32* __restrict__ ovCount, const u32* __restrict__ ovRow,
    const u32* __restrict__ ovRec, int N)
{
    __shared__ u32 ldsrec[4][64];
    const int lane = threadIdx.x & 63;
    const int wv   = threadIdx.x >> 6;
    const int row  = blockIdx.x * 4 + wv;
    if (row >= N) return;

    const int g = lane >> 3;
    const int j = lane & 7;

    const size_t base = ((size_t)g * N + row) << 4;
    u32 cg = packed[base];               // counter
    u32 pw = packed[base + 8 + j];       // this lane's slot (same line)
    u32 cgc = cg < (u32)GCAP ? cg : (u32)GCAP;

    u32 S = 0, degC = 0, degT = 0;
    bool ovf = false;
    #pragma unroll
    for (int gp = 0; gp < NG; ++gp) {
        u32 c = (u32)__shfl((int)cg, gp * 8);
        degT += c;
        ovf  |= (c > (u32)GCAP);
        u32 cc = c < (u32)GCAP ? c : (u32)GCAP;
        degC += cc;
        S += (gp < g) ? cc : 0u;
    }
    if (lane == 0) degOut[row] = degT;

    if ((u32)j < cgc) ldsrec[wv][S + j] = pw;

    const float2 wvv = ((const float2*)wc)[lane];
    const float2 cvv = ((const float2*)(wc + D))[lane];

    float a0[4] = {0.f, 0.f, 0.f, 0.f};
    float a1[4] = {0.f, 0.f, 0.f, 0.f};

    for (u32 base2 = 0; base2 < degC; base2 += 16) {
        u32 p[16], yv[16];
        #pragma unroll
        for (int kk = 0; kk < 16; ++kk) {
            u32 k = base2 + (u32)kk;
            if (k > degC - 1) k = degC - 1;
            p[kk] = ldsrec[wv][k];
        }
        #pragma unroll
        for (int kk = 0; kk < 16; ++kk)
            yv[kk] = *(const u32*)(ybf + (size_t)(p[kk] & 0xFFFFu) * D + 2 * lane);
        #pragma unroll
        for (int kk = 0; kk < 16; ++kk) {
            float dt = __half2float(__ushort_as_half((u16)(p[kk] >> 16)));
            float v0 = fmaxf(0.f, fmaf(dt, wvv.x, __uint_as_float(yv[kk] << 16)         + cvv.x));
            float v1 = fmaxf(0.f, fmaf(dt, wvv.y, __uint_as_float(yv[kk] & 0xFFFF0000u) + cvv.y));
            bool ok = (base2 + (u32)kk) < degC;
            a0[kk & 3] += ok ? v0 : 0.f;
            a1[kk & 3] += ok ? v1 : 0.f;
        }
    }

    if (ovf) {
        u32 ov = *ovCount; if (ov > (u32)OVMAX) ov = (u32)OVMAX;
        for (u32 i = 0; i < ov; ++i) {
            if (ovRow[i] == (u32)row) {
                u32 pr = ovRec[i];
                float dt = __half2float(__ushort_as_half((u16)(pr >> 16)));
                u32 yvv = *(const u32*)(ybf + (size_t)(pr & 0xFFFFu) * D + 2 * lane);
                a0[0] += fmaxf(0.f, fmaf(dt, wvv.x, __uint_as_float(yvv << 16)         + cvv.x));
                a1[0] += fmaxf(0.f, fmaf(dt, wvv.y, __uint_as_float(yvv & 0xFFFF0000u) + cvv.y));
            }
        }
    }
    float r0 = (a0[0] + a0[1]) + (a0[2] + a0[3]);
    float r1 = (a1[0] + a1[1]) + (a1[2] + a1[3]);
    Hb2[(size_t)row * 64 + lane] = (u32)f2bf(r0) | ((u32)f2bf(r1) << 16);
}

// ---------------------------------------------------------------------------
// GEMM2: out = f32(Hb @ W2 + x + deg*b2), K=D=128, MFMA 16x16x32 bf16.
// ---------------------------------------------------------------------------
__global__ __launch_bounds__(256) void gemm2_kernel(
    const u16* __restrict__ Asrc, const u16* __restrict__ Wt,
    const float* __restrict__ xres, const u32* __restrict__ degi,
    const float* __restrict__ bvec, float* __restrict__ out, int N)
{
    __shared__ u16 wl[D * LDAP];
    __shared__ u16 al[64 * LDAP];
    const int t    = threadIdx.x;
    const int lane = t & 63;
    const int w    = t >> 6;
    const int n0   = blockIdx.x * 64;

    #pragma unroll
    for (int i = 0; i < 8; ++i) {
        int e = (i * 256 + t) * 8;
        int r = e >> 7, c = e & 127;
        *(u32x4*)&wl[r * LDAP + c] = *(const u32x4*)&Wt[r * D + c];
    }
    #pragma unroll
    for (int i = 0; i < 4; ++i) {
        int idx = i * 256 + t;
        int r = idx >> 4, c8 = idx & 15;
        int gr = n0 + r; if (gr >= N) gr = N - 1;
        *(u32x4*)&al[r * LDAP + c8 * 8] = *(const u32x4*)&Asrc[(size_t)gr * D + c8 * 8];
    }
    __syncthreads();

    const int  fr     = lane & 15;
    const int  kg     = lane >> 4;
    const bool wvalid = (n0 + w * 16) < N;

    f32x4 acc[8];
    #pragma unroll
    for (int i = 0; i < 8; ++i) acc[i] = (f32x4){0.f, 0.f, 0.f, 0.f};

    #pragma unroll
    for (int kk = 0; kk < 4; ++kk) {
        const int ko = kk * 32 + kg * 8;
        s16x8 a = *(const s16x8*)&al[(w * 16 + fr) * LDAP + ko];
        #pragma unroll
        for (int ct = 0; ct < 8; ++ct) {
            s16x8 b = *(const s16x8*)&wl[(ct * 16 + fr) * LDAP + ko];
            acc[ct] = __builtin_amdgcn_mfma_f32_16x16x32_bf16(a, b, acc[ct], 0, 0, 0);
        }
    }
    if (!wvalid) return;

    float degf[4];
    #pragma unroll
    for (int j = 0; j < 4; ++j)
        degf[j] = (float)degi[n0 + w * 16 + 4 * kg + j];
    #pragma unroll
    for (int ct = 0; ct < 8; ++ct) {
        const int c  = ct * 16 + fr;
        const float bv = bvec[c];
        #pragma unroll
        for (int j = 0; j < 4; ++j) {
            int R = n0 + w * 16 + 4 * kg + j;
            float r = acc[ct][j] + xres[(size_t)R * D + c] + degf[j] * bv;
            out[(size_t)R * D + c] = r;
        }
    }
}

// ---------------------------------------------------------------------------
extern "C" void kernel_launch(void* const* d_in, const int* in_sizes, int n_in,
                              void* d_out, int out_size, void* d_ws, size_t ws_size,
                              hipStream_t stream)
{
    const float* x      = (const float*)d_in[0];
    const float* coord  = (const float*)d_in[1];
    const void*  eidx   = d_in[2];
    const float* W_edge = (const float*)d_in[3];
    const float* b_edge = (const float*)d_in[4];
    const float* W1     = (const float*)d_in[5];
    const float* b1     = (const float*)d_in[6];
    const float* W2     = (const float*)d_in[7];
    const float* b2     = (const float*)d_in[8];

    const int N = in_sizes[1] / 3;
    const int E = in_sizes[2] / 2;

    // ---- d_out scratch: packed units [NG*N][16 u32] = 64B/(row,group),
    //      counter word + 8 slots per unit. Exactly N*D*4 bytes = out size.
    //      Dead before gemm2 overwrites d_out.
    u32* packed = (u32*)d_out;

    // ---- d_ws: Hb [N*D bf16] | ybf [N*D bf16] | degOut [N u32]
    //            | wc [2D f32] | Wt1 | Wt2 | ovCount | ovRow | ovRec
    char* wsb     = (char*)d_ws;
    u16*  Hb      = (u16*)wsb;                size_t o = (size_t)N * D * 2;
    u16*  ybf     = (u16*)(wsb + o);          o += (size_t)N * D * 2;
    u32*  degOut  = (u32*)(wsb + o);          o += (size_t)N * 4 + 64;
    float* wc     = (float*)(wsb + o);        o += 2 * D * 4 + 64;
    u16*  Wt1     = (u16*)(wsb + o);          o += D * D * 2;
    u16*  Wt2     = (u16*)(wsb + o);          o += D * D * 2;
    u32*  ovCount = (u32*)(wsb + o);          o += 64;
    u32*  ovRow   = (u32*)(wsb + o);          o += OVMAX * 4;
    u32*  ovRec   = (u32*)(wsb + o);

    const int nunits = NG * N;
    const int ZB  = (nunits + 127) / 128;
    prep_zero_kernel<<<D + 1 + ZB, 128, 0, stream>>>(
        W_edge, b_edge, W1, b1, W2, wc, Wt1, Wt2, packed, nunits, ovCount);

    const int CB = (E + 255) / 256;            // count blocks (1 edge/thread)
    const int GB = (N + 63) / 64;              // gemm blocks
    count_gemm1_kernel<<<CB + GB, 256, 0, stream>>>(
        eidx, coord, packed, ovCount, ovRow, ovRec, E, CB,
        x, Wt1, ybf, N);

    aggregate_kernel<<<(N + 3) / 4, 256, 0, stream>>>(
        ybf, packed, wc, (u32*)Hb, degOut,
        ovCount, ovRow, ovRec, N);

    gemm2_kernel<<<GB, 256, 0, stream>>>(
        Hb, Wt2, x, degOut, b2, (float*)d_out, N);
}

// Round 17
// 91.842 us; speedup vs baseline: 1.1823x; 1.1823x over previous
//
#include <hip/hip_runtime.h>
#include <hip/hip_fp16.h>
#include <hip/hip_bf16.h>
#include <math.h>

#define D 128
#define LDAP 136      // padded LDS row length (bf16 elems)
#define NG 8          // block groups (== XCD count heuristic)
#define GCAP 8        // slots per (row, group); mean sub-degree 1.6
#define OVMAX 4096    // overflow list capacity (expected ~15 entries)

typedef unsigned int   u32;
typedef unsigned short u16;
using f32x4 = __attribute__((ext_vector_type(4))) float;
using s16x8 = __attribute__((ext_vector_type(8))) short;
using u32x4 = __attribute__((ext_vector_type(4))) unsigned int;

__device__ __forceinline__ u16 f2bf(float f) {       // RNE f32->bf16
    u32 u = __float_as_uint(f);
    return (u16)((u + 0x7FFFu + ((u >> 16) & 1u)) >> 16);
}

// ---------------------------------------------------------------------------
// Per-wave int64-vs-int32 edge_index detection (high words of first 64
// elements all zero => int64). Deterministic, same answer in every block.
// ---------------------------------------------------------------------------
__device__ __forceinline__ bool detect_is64(const int* __restrict__ idx32, int E) {
    int lane = threadIdx.x & 63;
    int hi = 0;
    if (lane < E) hi = idx32[2 * lane + 1];
    return __ballot(hi != 0) == 0ull;
}

// ---------------------------------------------------------------------------
// prep+zero: blocks 0..127 transpose W1_top/W2 to bf16; block 128 builds
// w_vec/c_vec + zeroes ovCount; blocks 129.. zero counts (NG*N words).
// ---------------------------------------------------------------------------
__global__ __launch_bounds__(128) void prep_zero_kernel(
    const float* __restrict__ W_edge, const float* __restrict__ b_edge,
    const float* __restrict__ W1, const float* __restrict__ b1,
    const float* __restrict__ W2, float* __restrict__ wc,
    u16* __restrict__ Wt1, u16* __restrict__ Wt2,
    u32x4* __restrict__ counts4, int nz4, u32* __restrict__ ovCount)
{
    const int b = blockIdx.x, t = threadIdx.x;
    if (b < D) {
        Wt1[b * D + t] = f2bf(W1[(size_t)t * D + b]);
        Wt2[b * D + t] = f2bf(W2[(size_t)t * D + b]);
    } else if (b == D) {
        if (t == 0) *ovCount = 0u;
        float w = 0.f, c = 0.f;
        #pragma unroll 8
        for (int k = 0; k < D; ++k) {
            float w1 = W1[(size_t)(D + k) * D + t];
            w = fmaf(W_edge[k], w1, w);
            c = fmaf(b_edge[k], w1, c);
        }
        wc[t]     = w;
        wc[D + t] = c + b1[t];
    } else {
        int i = (b - D - 1) * 128 + t;
        if (i < nz4) counts4[i] = (u32x4){0u, 0u, 0u, 0u};
    }
}

// ---------------------------------------------------------------------------
// FUSED count + gemm1 (R14 structure, proven 92.2us total).
// Blocks [0,CB): count path, group g = bid & 7 (XCD-local counts/packed:
// R12 confirmed local-L2 atomics). Low-word eidx reads only (indices < 2^31).
// Blocks [CB,CB+GB): gemm1 path — MFMA backfills the idle matrix pipe.
// ---------------------------------------------------------------------------
__global__ __launch_bounds__(256) void count_gemm1_kernel(
    const void* __restrict__ eidx, const float* __restrict__ coord,
    u32* __restrict__ counts, u32* __restrict__ packed,
    u32* __restrict__ ovCount, u32* __restrict__ ovRow,
    u32* __restrict__ ovRec, int E, int CB,
    const float* __restrict__ A, const u16* __restrict__ Wt,
    u16* __restrict__ ybf, int N)
{
    __shared__ u16 wl[D * LDAP];
    __shared__ u16 al[64 * LDAP];

    if ((int)blockIdx.x < CB) {
        // ---------------- count path ----------------
        const int* idx32 = (const int*)eidx;
        const bool is64 = detect_is64(idx32, E);
        const int g = (int)(blockIdx.x & (NG - 1));
        const int e = blockIdx.x * 256 + threadIdx.x;
        if (e >= E) return;

        int row = is64 ? idx32[2 * e]       : idx32[e];
        int col = is64 ? idx32[2 * (E + e)] : idx32[E + e];

        u32 seq = atomicAdd(&counts[(size_t)g * N + row], 1u);

        float dx = coord[3 * row + 0] - coord[3 * col + 0];
        float dy = coord[3 * row + 1] - coord[3 * col + 1];
        float dz = coord[3 * row + 2] - coord[3 * col + 2];
        float dist = sqrtf(fmaf(dx, dx, fmaf(dy, dy, dz * dz)));
        u32 rec = (u32)col | ((u32)__half_as_ushort(__float2half(dist)) << 16);

        if (seq < (u32)GCAP) {
            packed[(((size_t)g * N + row) << 3) + seq] = rec;
        } else {
            u32 k = atomicAdd(ovCount, 1u);
            if (k < (u32)OVMAX) { ovRow[k] = (u32)row; ovRec[k] = rec; }
        }
        return;
    }

    // ---------------- gemm1 path ----------------
    const int bid  = blockIdx.x - CB;
    const int t    = threadIdx.x;
    const int lane = t & 63;
    const int w    = t >> 6;
    const int n0   = bid * 64;

    #pragma unroll
    for (int i = 0; i < 8; ++i) {
        int e = (i * 256 + t) * 8;
        int r = e >> 7, c = e & 127;
        *(u32x4*)&wl[r * LDAP + c] = *(const u32x4*)&Wt[r * D + c];
    }
    #pragma unroll
    for (int i = 0; i < 8; ++i) {
        int idx = i * 256 + t;
        int r = idx >> 5, c4 = idx & 31;
        int gr = n0 + r; if (gr >= N) gr = N - 1;
        float4 v = *(const float4*)&A[(size_t)gr * D + c4 * 4];
        u32 lo = (u32)f2bf(v.x) | ((u32)f2bf(v.y) << 16);
        u32 hi = (u32)f2bf(v.z) | ((u32)f2bf(v.w) << 16);
        *(uint2*)&al[r * LDAP + c4 * 4] = make_uint2(lo, hi);
    }
    __syncthreads();

    const int  fr     = lane & 15;
    const int  kg     = lane >> 4;
    const bool wvalid = (n0 + w * 16) < N;

    f32x4 acc[8];
    #pragma unroll
    for (int i = 0; i < 8; ++i) acc[i] = (f32x4){0.f, 0.f, 0.f, 0.f};

    #pragma unroll
    for (int kk = 0; kk < 4; ++kk) {
        const int ko = kk * 32 + kg * 8;
        s16x8 a = *(const s16x8*)&al[(w * 16 + fr) * LDAP + ko];
        #pragma unroll
        for (int ct = 0; ct < 8; ++ct) {
            s16x8 b = *(const s16x8*)&wl[(ct * 16 + fr) * LDAP + ko];
            acc[ct] = __builtin_amdgcn_mfma_f32_16x16x32_bf16(a, b, acc[ct], 0, 0, 0);
        }
    }
    if (!wvalid) return;

    #pragma unroll
    for (int ct = 0; ct < 8; ++ct) {
        const int c = ct * 16 + fr;
        #pragma unroll
        for (int j = 0; j < 4; ++j) {
            int R = n0 + w * 16 + 4 * kg + j;
            ybf[(size_t)R * D + c] = f2bf(acc[ct][j]);
        }
    }
}

// ---------------------------------------------------------------------------
// pull aggregation -> H bf16 + degOut. One wave/row; lane owns chans 2l,2l+1.
// Step 1: lane l owns sub-bucket slot (g=l>>3, j=l&7); 1 counts + 1 packed
// load per lane; group prefix via 8 shfls; dense-compact into per-wave LDS.
// Step 2: proven R11 loop (LDS broadcast records, 16 uncond y-gathers,
// masked accumulate).
// ---------------------------------------------------------------------------
__global__ __launch_bounds__(256) void aggregate_kernel(
    const u16* __restrict__ ybf, const u32* __restrict__ counts,
    const u32* __restrict__ packed, const float* __restrict__ wc,
    u32* __restrict__ Hb2, u32* __restrict__ degOut,
    const u32* __restrict__ ovCount, const u32* __restrict__ ovRow,
    const u32* __restrict__ ovRec, int N)
{
    __shared__ u32 ldsrec[4][64];
    const int lane = threadIdx.x & 63;
    const int wv   = threadIdx.x >> 6;
    const int row  = blockIdx.x * 4 + wv;
    if (row >= N) return;

    const int g = lane >> 3;
    const int j = lane & 7;

    u32 cg = counts[(size_t)g * N + row];
    u32 pw = packed[(((size_t)g * N + row) << 3) + j];
    u32 cgc = cg < (u32)GCAP ? cg : (u32)GCAP;

    u32 S = 0, degC = 0, degT = 0;
    bool ovf = false;
    #pragma unroll
    for (int gp = 0; gp < NG; ++gp) {
        u32 c = (u32)__shfl((int)cg, gp * 8);
        degT += c;
        ovf  |= (c > (u32)GCAP);
        u32 cc = c < (u32)GCAP ? c : (u32)GCAP;
        degC += cc;
        S += (gp < g) ? cc : 0u;
    }
    if (lane == 0) degOut[row] = degT;

    if ((u32)j < cgc) ldsrec[wv][S + j] = pw;

    const float2 wvv = ((const float2*)wc)[lane];
    const float2 cvv = ((const float2*)(wc + D))[lane];

    float a0[4] = {0.f, 0.f, 0.f, 0.f};
    float a1[4] = {0.f, 0.f, 0.f, 0.f};

    for (u32 base = 0; base < degC; base += 16) {
        u32 p[16], yv[16];
        #pragma unroll
        for (int kk = 0; kk < 16; ++kk) {
            u32 k = base + (u32)kk;
            if (k > degC - 1) k = degC - 1;
            p[kk] = ldsrec[wv][k];
        }
        #pragma unroll
        for (int kk = 0; kk < 16; ++kk)
            yv[kk] = *(const u32*)(ybf + (size_t)(p[kk] & 0xFFFFu) * D + 2 * lane);
        #pragma unroll
        for (int kk = 0; kk < 16; ++kk) {
            float dt = __half2float(__ushort_as_half((u16)(p[kk] >> 16)));
            float v0 = fmaxf(0.f, fmaf(dt, wvv.x, __uint_as_float(yv[kk] << 16)         + cvv.x));
            float v1 = fmaxf(0.f, fmaf(dt, wvv.y, __uint_as_float(yv[kk] & 0xFFFF0000u) + cvv.y));
            bool ok = (base + (u32)kk) < degC;
            a0[kk & 3] += ok ? v0 : 0.f;
            a1[kk & 3] += ok ? v1 : 0.f;
        }
    }

    if (ovf) {
        u32 ov = *ovCount; if (ov > (u32)OVMAX) ov = (u32)OVMAX;
        for (u32 i = 0; i < ov; ++i) {
            if (ovRow[i] == (u32)row) {
                u32 pr = ovRec[i];
                float dt = __half2float(__ushort_as_half((u16)(pr >> 16)));
                u32 yvv = *(const u32*)(ybf + (size_t)(pr & 0xFFFFu) * D + 2 * lane);
                a0[0] += fmaxf(0.f, fmaf(dt, wvv.x, __uint_as_float(yvv << 16)         + cvv.x));
                a1[0] += fmaxf(0.f, fmaf(dt, wvv.y, __uint_as_float(yvv & 0xFFFF0000u) + cvv.y));
            }
        }
    }
    float r0 = (a0[0] + a0[1]) + (a0[2] + a0[3]);
    float r1 = (a1[0] + a1[1]) + (a1[2] + a1[3]);
    Hb2[(size_t)row * 64 + lane] = (u32)f2bf(r0) | ((u32)f2bf(r1) << 16);
}

// ---------------------------------------------------------------------------
// GEMM2: out = f32(Hb @ W2 + x + deg*b2), K=D=128, MFMA 16x16x32 bf16.
// ---------------------------------------------------------------------------
__global__ __launch_bounds__(256) void gemm2_kernel(
    const u16* __restrict__ Asrc, const u16* __restrict__ Wt,
    const float* __restrict__ xres, const u32* __restrict__ degi,
    const float* __restrict__ bvec, float* __restrict__ out, int N)
{
    __shared__ u16 wl[D * LDAP];
    __shared__ u16 al[64 * LDAP];
    const int t    = threadIdx.x;
    const int lane = t & 63;
    const int w    = t >> 6;
    const int n0   = blockIdx.x * 64;

    #pragma unroll
    for (int i = 0; i < 8; ++i) {
        int e = (i * 256 + t) * 8;
        int r = e >> 7, c = e & 127;
        *(u32x4*)&wl[r * LDAP + c] = *(const u32x4*)&Wt[r * D + c];
    }
    #pragma unroll
    for (int i = 0; i < 4; ++i) {
        int idx = i * 256 + t;
        int r = idx >> 4, c8 = idx & 15;
        int gr = n0 + r; if (gr >= N) gr = N - 1;
        *(u32x4*)&al[r * LDAP + c8 * 8] = *(const u32x4*)&Asrc[(size_t)gr * D + c8 * 8];
    }
    __syncthreads();

    const int  fr     = lane & 15;
    const int  kg     = lane >> 4;
    const bool wvalid = (n0 + w * 16) < N;

    f32x4 acc[8];
    #pragma unroll
    for (int i = 0; i < 8; ++i) acc[i] = (f32x4){0.f, 0.f, 0.f, 0.f};

    #pragma unroll
    for (int kk = 0; kk < 4; ++kk) {
        const int ko = kk * 32 + kg * 8;
        s16x8 a = *(const s16x8*)&al[(w * 16 + fr) * LDAP + ko];
        #pragma unroll
        for (int ct = 0; ct < 8; ++ct) {
            s16x8 b = *(const s16x8*)&wl[(ct * 16 + fr) * LDAP + ko];
            acc[ct] = __builtin_amdgcn_mfma_f32_16x16x32_bf16(a, b, acc[ct], 0, 0, 0);
        }
    }
    if (!wvalid) return;

    float degf[4];
    #pragma unroll
    for (int j = 0; j < 4; ++j)
        degf[j] = (float)degi[n0 + w * 16 + 4 * kg + j];
    #pragma unroll
    for (int ct = 0; ct < 8; ++ct) {
        const int c  = ct * 16 + fr;
        const float bv = bvec[c];
        #pragma unroll
        for (int j = 0; j < 4; ++j) {
            int R = n0 + w * 16 + 4 * kg + j;
            float r = acc[ct][j] + xres[(size_t)R * D + c] + degf[j] * bv;
            out[(size_t)R * D + c] = r;
        }
    }
}

// ---------------------------------------------------------------------------
extern "C" void kernel_launch(void* const* d_in, const int* in_sizes, int n_in,
                              void* d_out, int out_size, void* d_ws, size_t ws_size,
                              hipStream_t stream)
{
    const float* x      = (const float*)d_in[0];
    const float* coord  = (const float*)d_in[1];
    const void*  eidx   = d_in[2];
    const float* W_edge = (const float*)d_in[3];
    const float* b_edge = (const float*)d_in[4];
    const float* W1     = (const float*)d_in[5];
    const float* b1     = (const float*)d_in[6];
    const float* W2     = (const float*)d_in[7];
    const float* b2     = (const float*)d_in[8];

    const int N = in_sizes[1] / 3;
    const int E = in_sizes[2] / 2;

    // ---- d_ws: Hb [N*D bf16] | counts [NG*N u32] | degOut [N u32]
    //            | wc [2D f32] | Wt1 | Wt2 | ovCount | ovRow | ovRec
    char* wsb     = (char*)d_ws;
    u16*  Hb      = (u16*)wsb;                size_t o = (size_t)N * D * 2;
    u32*  counts  = (u32*)(wsb + o);          o += (size_t)NG * N * 4 + 64;
    u32*  degOut  = (u32*)(wsb + o);          o += (size_t)N * 4 + 64;
    float* wc     = (float*)(wsb + o);        o += 2 * D * 4 + 64;
    u16*  Wt1     = (u16*)(wsb + o);          o += D * D * 2;
    u16*  Wt2     = (u16*)(wsb + o);          o += D * D * 2;
    u32*  ovCount = (u32*)(wsb + o);          o += 64;
    u32*  ovRow   = (u32*)(wsb + o);          o += OVMAX * 4;
    u32*  ovRec   = (u32*)(wsb + o);

    // ---- d_out scratch: ybf [N*D bf16] | packed [NG*N*GCAP u32]
    //      (12.8 MB + 12.8 MB = exactly d_out; dead before gemm2 writes)
    char* ob     = (char*)d_out;
    u16*  ybf    = (u16*)ob;
    u32*  packed = (u32*)(ob + (size_t)N * D * 2);

    const int nz4 = (NG * N + 3) / 4;
    const int ZB  = (nz4 + 127) / 128;
    prep_zero_kernel<<<D + 1 + ZB, 128, 0, stream>>>(
        W_edge, b_edge, W1, b1, W2, wc, Wt1, Wt2, (u32x4*)counts, nz4, ovCount);

    const int CB = (E + 255) / 256;            // count blocks (1 edge/thread)
    const int GB = (N + 63) / 64;              // gemm blocks
    count_gemm1_kernel<<<CB + GB, 256, 0, stream>>>(
        eidx, coord, counts, packed, ovCount, ovRow, ovRec, E, CB,
        x, Wt1, ybf, N);

    aggregate_kernel<<<(N + 3) / 4, 256, 0, stream>>>(
        ybf, counts, packed, wc, (u32*)Hb, degOut,
        ovCount, ovRow, ovRec, N);

    gemm2_kernel<<<GB, 256, 0, stream>>>(
        Hb, Wt2, x, degOut, b2, (float*)d_out, N);
}